// Round 8
// baseline (477.130 us; speedup 1.0000x reference)
//
#include <hip/hip_runtime.h>

#define C_IN 256
#define C_OUT 64
#define BSH 7                 // bucket = dst >> 7  (128 nodes/bucket)
#define NPB 128               // nodes per bucket
#define NB 1024               // max buckets (n <= 131072)
#define CHUNK 8192            // edges per binning block
#define LDK 264               // padded row stride (ushorts): 256 + 8 -> 528 B

typedef short bf16x8 __attribute__((ext_vector_type(8)));
typedef float f32x4 __attribute__((ext_vector_type(4)));

__device__ __forceinline__ unsigned short f2bf(float f) {
    unsigned u = __builtin_bit_cast(unsigned, f);
    u = (u + 0x7FFFu + ((u >> 16) & 1u)) >> 16;
    return (unsigned short)u;
}
__device__ __forceinline__ float bflo(unsigned u) {
    return __builtin_bit_cast(float, u << 16);
}
__device__ __forceinline__ float bfhi(unsigned u) {
    return __builtin_bit_cast(float, u & 0xffff0000u);
}

// ---------------- per-(block,bucket) histogram table ----------------
__global__ __launch_bounds__(256) void k_hist2(const int* __restrict__ dst,
                                               int* __restrict__ table, int e) {
    __shared__ int cnt[NB];
    for (int j = threadIdx.x; j < NB; j += 256) cnt[j] = 0;
    __syncthreads();
    int b0 = blockIdx.x * CHUNK;
#pragma unroll 4
    for (int k = 0; k < CHUNK / 256; ++k) {
        int i = b0 + k * 256 + threadIdx.x;
        if (i < e) atomicAdd(&cnt[dst[i] >> BSH], 1);
    }
    __syncthreads();
    int* row = table + (size_t)blockIdx.x * NB;
    for (int j = threadIdx.x; j < NB; j += 256) row[j] = cnt[j];
}

// ---------------- column-wise exclusive scan over blocks ----------------
// thread <-> bucket; 16 blocks x 64 threads
__global__ __launch_bounds__(64) void kA(int* __restrict__ table,
                                         int* __restrict__ tot, int nbin) {
    int t = blockIdx.x * 64 + threadIdx.x;   // bucket id
    int run = 0;
    for (int b = 0; b < nbin; ++b) {
        int v = table[(size_t)b * NB + t];
        table[(size_t)b * NB + t] = run;
        run += v;
    }
    tot[t] = run;
}

// ---------------- bucket totals -> compact gbase ----------------
__global__ __launch_bounds__(1024) void kB(const int* __restrict__ tot,
                                           int* __restrict__ gbase, int e) {
    __shared__ int l[NB];
    int t = threadIdx.x;
    int v = tot[t];
    l[t] = v;
    __syncthreads();
    for (int off = 1; off < NB; off <<= 1) {
        int u = (t >= off) ? l[t - off] : 0;
        __syncthreads();
        l[t] += u;
        __syncthreads();
    }
    gbase[t] = l[t] - v;  // exclusive
    if (t == NB - 1) gbase[NB] = e;
}

// ---------------- single-pass atomic-free multisplit ----------------
__global__ __launch_bounds__(256) void k_bin2(const int* __restrict__ src,
                                              const int* __restrict__ dst,
                                              const int* __restrict__ table,
                                              const int* __restrict__ gbase,
                                              int* __restrict__ sorted, int e) {
    __shared__ int cur[NB];
    const int* row = table + (size_t)blockIdx.x * NB;
    for (int j = threadIdx.x; j < NB; j += 256) cur[j] = row[j] + gbase[j];
    __syncthreads();
    int b0 = blockIdx.x * CHUNK;
#pragma unroll 4
    for (int k = 0; k < CHUNK / 256; ++k) {
        int i = b0 + k * 256 + threadIdx.x;
        if (i < e) {
            int d = dst[i];
            int bb = d >> BSH;
            int off = atomicAdd(&cur[bb], 1);
            sorted[off] = (src[i] << BSH) | (d & (NPB - 1));
        }
    }
}

// ---------------- in-bucket counting sort -> per-node CSR, plus dinv ----------------
__global__ __launch_bounds__(256) void k_sort2(const int* __restrict__ sorted,
                                               const int* __restrict__ gbase,
                                               int* __restrict__ eidx,
                                               int* __restrict__ rowptr,
                                               float* __restrict__ dinv, int n, int e) {
    __shared__ int cnt[NPB];
    __shared__ int sc[NPB];
    __shared__ int cur[NPB];
    int b = blockIdx.x;
    int node0 = b * NPB;
    int range = min(NPB, n - node0);
    int inbase = gbase[b];
    int m_b = gbase[b + 1] - inbase;
    if (threadIdx.x < NPB) cnt[threadIdx.x] = 0;
    __syncthreads();
    for (int j = threadIdx.x; j < m_b; j += 256)
        atomicAdd(&cnt[sorted[inbase + j] & (NPB - 1)], 1);
    __syncthreads();
    if (threadIdx.x < NPB) sc[threadIdx.x] = cnt[threadIdx.x];
    __syncthreads();
    for (int off = 1; off < NPB; off <<= 1) {
        int t = (threadIdx.x < NPB && threadIdx.x >= off) ? sc[threadIdx.x - off] : 0;
        __syncthreads();
        if (threadIdx.x < NPB) sc[threadIdx.x] += t;
        __syncthreads();
    }
    if (threadIdx.x < NPB) {
        int excl = inbase + sc[threadIdx.x] - cnt[threadIdx.x];
        cur[threadIdx.x] = excl;
        if (threadIdx.x < range) {
            rowptr[node0 + threadIdx.x] = excl;
            dinv[node0 + threadIdx.x] = rsqrtf((float)(cnt[threadIdx.x] + 1));
        }
    }
    __syncthreads();
    for (int j = threadIdx.x; j < m_b; j += 256) {
        int v = sorted[inbase + j];
        int pos = atomicAdd(&cur[v & (NPB - 1)], 1);
        eidx[pos] = v >> BSH;
    }
    if (b == 0 && threadIdx.x == 0) rowptr[n] = e;
}

// ---------------- h = x @ W via bf16 MFMA (bf16 output) ----------------
__global__ __launch_bounds__(256) void k_gemm(const float* __restrict__ x,
                                              const float* __restrict__ W,
                                              unsigned short* __restrict__ h, int n) {
    __shared__ unsigned short Xl[64 * LDK];
    __shared__ unsigned short Wl[64 * LDK];  // transposed: Wl[n][k]

    const int t = threadIdx.x;
    const int row0 = blockIdx.x * 64;

#pragma unroll
    for (int i = 0; i < 16; ++i) {
        int f = i * 256 + t;
        int k = f >> 4;
        int n4 = (f & 15) * 4;
        float4 v = ((const float4*)W)[f];
        Wl[(n4 + 0) * LDK + k] = f2bf(v.x);
        Wl[(n4 + 1) * LDK + k] = f2bf(v.y);
        Wl[(n4 + 2) * LDK + k] = f2bf(v.z);
        Wl[(n4 + 3) * LDK + k] = f2bf(v.w);
    }
#pragma unroll
    for (int i = 0; i < 16; ++i) {
        int f = i * 256 + t;
        int row = f >> 6;
        int c4 = f & 63;
        int gr = row0 + row;
        float4 v = (gr < n) ? ((const float4*)x)[(size_t)gr * 64 + c4]
                            : make_float4(0.f, 0.f, 0.f, 0.f);
        unsigned short* p = &Xl[row * LDK + c4 * 4];
        ushort4 o;
        o.x = f2bf(v.x); o.y = f2bf(v.y); o.z = f2bf(v.z); o.w = f2bf(v.w);
        *(ushort4*)p = o;
    }
    __syncthreads();

    const int lane = t & 63;
    const int w = t >> 6;
    const int m = lane & 15;
    const int q = lane >> 4;

    f32x4 acc[4];
#pragma unroll
    for (int nt = 0; nt < 4; ++nt) acc[nt] = (f32x4){0.f, 0.f, 0.f, 0.f};

#pragma unroll
    for (int ks = 0; ks < 8; ++ks) {
        bf16x8 A = *(const bf16x8*)&Xl[(16 * w + m) * LDK + ks * 32 + q * 8];
#pragma unroll
        for (int nt = 0; nt < 4; ++nt) {
            bf16x8 B = *(const bf16x8*)&Wl[(16 * nt + m) * LDK + ks * 32 + q * 8];
            acc[nt] = __builtin_amdgcn_mfma_f32_16x16x32_bf16(A, B, acc[nt], 0, 0, 0);
        }
    }

#pragma unroll
    for (int nt = 0; nt < 4; ++nt) {
#pragma unroll
        for (int r = 0; r < 4; ++r) {
            int gr = row0 + 16 * w + q * 4 + r;
            if (gr < n) h[(size_t)gr * C_OUT + nt * 16 + m] = f2bf(acc[nt][r]);
        }
    }
}

// ---------------- gather: 1 wave per node, 2 edges/iter (half-wave each) ----------------
__global__ __launch_bounds__(256) void k_gather(const int* __restrict__ rowptr,
                                                const int* __restrict__ eidx,
                                                const unsigned short* __restrict__ h,
                                                const float* __restrict__ dinv,
                                                const float* __restrict__ bias,
                                                float* __restrict__ out, int n) {
    int node = blockIdx.x * 4 + (threadIdx.x >> 6);
    if (node >= n) return;
    int lane = threadIdx.x & 63;
    int half = lane >> 5;
    int c2 = (lane & 31) * 2;

    int beg = rowptr[node];
    int end = rowptr[node + 1];
    float di = dinv[node];
    float ax = 0.f, ay = 0.f;

    int j = beg;
    for (; j + 7 < end; j += 8) {
        int s0 = eidx[j + half];
        int s1 = eidx[j + 2 + half];
        int s2 = eidx[j + 4 + half];
        int s3 = eidx[j + 6 + half];
        float d0 = dinv[s0], d1 = dinv[s1], d2 = dinv[s2], d3 = dinv[s3];
        unsigned h0 = *(const unsigned*)&h[(size_t)s0 * C_OUT + c2];
        unsigned h1 = *(const unsigned*)&h[(size_t)s1 * C_OUT + c2];
        unsigned h2 = *(const unsigned*)&h[(size_t)s2 * C_OUT + c2];
        unsigned h3 = *(const unsigned*)&h[(size_t)s3 * C_OUT + c2];
        ax += bflo(h0) * d0; ay += bfhi(h0) * d0;
        ax += bflo(h1) * d1; ay += bfhi(h1) * d1;
        ax += bflo(h2) * d2; ay += bfhi(h2) * d2;
        ax += bflo(h3) * d3; ay += bfhi(h3) * d3;
    }
    for (; j < end; j += 2) {
        int rem = end - j;
        int idx = j + ((half < rem) ? half : 0);
        int s = eidx[idx];
        float d = (half < rem) ? dinv[s] : 0.f;
        unsigned hv = *(const unsigned*)&h[(size_t)s * C_OUT + c2];
        ax += bflo(hv) * d; ay += bfhi(hv) * d;
    }
    ax += __shfl_xor(ax, 32, 64);
    ay += __shfl_xor(ay, 32, 64);
    if (half == 0) {
        unsigned sv = *(const unsigned*)&h[(size_t)node * C_OUT + c2];
        float2 bb = *(const float2*)&bias[c2];
        float2 o;
        o.x = ax * di + bflo(sv) * di * di + bb.x;
        o.y = ay * di + bfhi(sv) * di * di + bb.y;
        *(float2*)&out[(size_t)node * C_OUT + c2] = o;
    }
}

extern "C" void kernel_launch(void* const* d_in, const int* in_sizes, int n_in,
                              void* d_out, int out_size, void* d_ws, size_t ws_size,
                              hipStream_t stream) {
    const float* x = (const float*)d_in[0];
    const int* ei = (const int*)d_in[1];
    const float* W = (const float*)d_in[2];
    const float* bias = (const float*)d_in[3];
    float* out = (float*)d_out;

    const int n = in_sizes[0] / C_IN;  // 100000
    const int e = in_sizes[1] / 2;     // 3200000
    const int* src = ei;
    const int* dst = ei + e;

    const int nbin = (e + CHUNK - 1) / CHUNK;   // 391
    const int nbuck = (n + NPB - 1) / NPB;      // 782

    char* w = (char*)d_ws;
    unsigned short* h = (unsigned short*)w;  w += (size_t)n * C_OUT * 2;   // 12.8 MB
    int* sorted = (int*)w;                   w += (size_t)e * 4;           // 12.8 MB
    int* eidx = (int*)w;                     w += (size_t)e * 4;           // 12.8 MB
    float* dinv = (float*)w;                 w += (size_t)n * 4;
    int* rowptr = (int*)w;                   w += (size_t)(n + 1) * 4;
    int* table = (int*)w;                    w += (size_t)nbin * NB * 4;   // 1.6 MB
    int* tot = (int*)w;                      w += NB * 4;
    int* gbase = (int*)w;                    w += (NB + 1) * 4;

    k_hist2<<<nbin, 256, 0, stream>>>(dst, table, e);
    kA<<<NB / 64, 64, 0, stream>>>(table, tot, nbin);
    kB<<<1, 1024, 0, stream>>>(tot, gbase, e);
    k_bin2<<<nbin, 256, 0, stream>>>(src, dst, table, gbase, sorted, e);
    k_gemm<<<(n + 63) / 64, 256, 0, stream>>>(x, W, h, n);
    k_sort2<<<nbuck, 256, 0, stream>>>(sorted, gbase, eidx, rowptr, dinv, n, e);
    k_gather<<<(n + 3) / 4, 256, 0, stream>>>(rowptr, eidx, h, dinv, bias, out, n);
}

// Round 9
// 384.167 us; speedup vs baseline: 1.2420x; 1.2420x over previous
//
#include <hip/hip_runtime.h>

#define C_IN 256
#define C_OUT 64
#define BSH 7                 // bucket = dst >> 7  (128 nodes/bucket)
#define NPB 128               // nodes per bucket
#define NB 1024               // max buckets (n <= 131072)
#define CHUNK 8192            // edges per binning block
#define LDK 264               // padded row stride (ushorts): 256 + 8 -> 528 B

typedef short bf16x8 __attribute__((ext_vector_type(8)));
typedef float f32x4 __attribute__((ext_vector_type(4)));

__device__ __forceinline__ unsigned short f2bf(float f) {
    unsigned u = __builtin_bit_cast(unsigned, f);
    u = (u + 0x7FFFu + ((u >> 16) & 1u)) >> 16;
    return (unsigned short)u;
}
__device__ __forceinline__ float bflo(unsigned u) {
    return __builtin_bit_cast(float, u << 16);
}
__device__ __forceinline__ float bfhi(unsigned u) {
    return __builtin_bit_cast(float, u & 0xffff0000u);
}

// ---------------- per-(block,bucket) histogram table ----------------
__global__ __launch_bounds__(256) void k_hist2(const int* __restrict__ dst,
                                               int* __restrict__ table, int e) {
    __shared__ int cnt[NB];
    for (int j = threadIdx.x; j < NB; j += 256) cnt[j] = 0;
    __syncthreads();
    int b0 = blockIdx.x * CHUNK;
#pragma unroll 4
    for (int k = 0; k < CHUNK / 256; ++k) {
        int i = b0 + k * 256 + threadIdx.x;
        if (i < e) atomicAdd(&cnt[dst[i] >> BSH], 1);
    }
    __syncthreads();
    int* row = table + (size_t)blockIdx.x * NB;
    for (int j = threadIdx.x; j < NB; j += 256) row[j] = cnt[j];
}

// ---------------- column-wise exclusive scan: one block per bucket ----------------
__global__ __launch_bounds__(256) void kA2(int* __restrict__ table,
                                           int* __restrict__ tot, int nbin) {
    __shared__ int l[512];
    int bucket = blockIdx.x;
    int t = threadIdx.x;
    int v0 = (t < nbin) ? table[(size_t)t * NB + bucket] : 0;
    int v1 = (t + 256 < nbin) ? table[(size_t)(t + 256) * NB + bucket] : 0;
    l[t] = v0;
    l[t + 256] = v1;
    __syncthreads();
    for (int off = 1; off < 512; off <<= 1) {
        int u0 = (t >= off) ? l[t - off] : 0;
        int u1 = (t + 256 >= off) ? l[t + 256 - off] : 0;
        __syncthreads();
        l[t] += u0;
        l[t + 256] += u1;
        __syncthreads();
    }
    if (t < nbin) table[(size_t)t * NB + bucket] = l[t] - v0;
    if (t + 256 < nbin) table[(size_t)(t + 256) * NB + bucket] = l[t + 256] - v1;
    if (t == 255) tot[bucket] = l[511];
}

// ---------------- bucket totals -> compact gbase ----------------
__global__ __launch_bounds__(1024) void kB(const int* __restrict__ tot,
                                           int* __restrict__ gbase, int e) {
    __shared__ int l[NB];
    int t = threadIdx.x;
    int v = tot[t];
    l[t] = v;
    __syncthreads();
    for (int off = 1; off < NB; off <<= 1) {
        int u = (t >= off) ? l[t - off] : 0;
        __syncthreads();
        l[t] += u;
        __syncthreads();
    }
    gbase[t] = l[t] - v;  // exclusive
    if (t == NB - 1) gbase[NB] = e;
}

// ---------------- single-pass atomic-free multisplit ----------------
__global__ __launch_bounds__(256) void k_bin2(const int* __restrict__ src,
                                              const int* __restrict__ dst,
                                              const int* __restrict__ table,
                                              const int* __restrict__ gbase,
                                              int* __restrict__ sorted, int e) {
    __shared__ int cur[NB];
    const int* row = table + (size_t)blockIdx.x * NB;
    for (int j = threadIdx.x; j < NB; j += 256) cur[j] = row[j] + gbase[j];
    __syncthreads();
    int b0 = blockIdx.x * CHUNK;
#pragma unroll 4
    for (int k = 0; k < CHUNK / 256; ++k) {
        int i = b0 + k * 256 + threadIdx.x;
        if (i < e) {
            int d = dst[i];
            int bb = d >> BSH;
            int off = atomicAdd(&cur[bb], 1);
            sorted[off] = (src[i] << BSH) | (d & (NPB - 1));
        }
    }
}

// ---------------- in-bucket counting sort -> per-node CSR, plus dinv ----------------
__global__ __launch_bounds__(256) void k_sort2(const int* __restrict__ sorted,
                                               const int* __restrict__ gbase,
                                               int* __restrict__ eidx,
                                               int* __restrict__ rowptr,
                                               float* __restrict__ dinv, int n, int e) {
    __shared__ int cnt[NPB];
    __shared__ int sc[NPB];
    __shared__ int cur[NPB];
    int b = blockIdx.x;
    int node0 = b * NPB;
    int range = min(NPB, n - node0);
    int inbase = gbase[b];
    int m_b = gbase[b + 1] - inbase;
    if (threadIdx.x < NPB) cnt[threadIdx.x] = 0;
    __syncthreads();
    for (int j = threadIdx.x; j < m_b; j += 256)
        atomicAdd(&cnt[sorted[inbase + j] & (NPB - 1)], 1);
    __syncthreads();
    if (threadIdx.x < NPB) sc[threadIdx.x] = cnt[threadIdx.x];
    __syncthreads();
    for (int off = 1; off < NPB; off <<= 1) {
        int t = (threadIdx.x < NPB && threadIdx.x >= off) ? sc[threadIdx.x - off] : 0;
        __syncthreads();
        if (threadIdx.x < NPB) sc[threadIdx.x] += t;
        __syncthreads();
    }
    if (threadIdx.x < NPB) {
        int excl = inbase + sc[threadIdx.x] - cnt[threadIdx.x];
        cur[threadIdx.x] = excl;
        if (threadIdx.x < range) {
            rowptr[node0 + threadIdx.x] = excl;
            dinv[node0 + threadIdx.x] = rsqrtf((float)(cnt[threadIdx.x] + 1));
        }
    }
    __syncthreads();
    for (int j = threadIdx.x; j < m_b; j += 256) {
        int v = sorted[inbase + j];
        int pos = atomicAdd(&cur[v & (NPB - 1)], 1);
        eidx[pos] = v >> BSH;
    }
    if (b == 0 && threadIdx.x == 0) rowptr[n] = e;
}

// ---------------- h = x @ W via bf16 MFMA (bf16 output) ----------------
__global__ __launch_bounds__(256) void k_gemm(const float* __restrict__ x,
                                              const float* __restrict__ W,
                                              unsigned short* __restrict__ h, int n) {
    __shared__ unsigned short Xl[64 * LDK];
    __shared__ unsigned short Wl[64 * LDK];  // transposed: Wl[n][k]

    const int t = threadIdx.x;
    const int row0 = blockIdx.x * 64;

#pragma unroll
    for (int i = 0; i < 16; ++i) {
        int f = i * 256 + t;
        int k = f >> 4;
        int n4 = (f & 15) * 4;
        float4 v = ((const float4*)W)[f];
        Wl[(n4 + 0) * LDK + k] = f2bf(v.x);
        Wl[(n4 + 1) * LDK + k] = f2bf(v.y);
        Wl[(n4 + 2) * LDK + k] = f2bf(v.z);
        Wl[(n4 + 3) * LDK + k] = f2bf(v.w);
    }
#pragma unroll
    for (int i = 0; i < 16; ++i) {
        int f = i * 256 + t;
        int row = f >> 6;
        int c4 = f & 63;
        int gr = row0 + row;
        float4 v = (gr < n) ? ((const float4*)x)[(size_t)gr * 64 + c4]
                            : make_float4(0.f, 0.f, 0.f, 0.f);
        unsigned short* p = &Xl[row * LDK + c4 * 4];
        ushort4 o;
        o.x = f2bf(v.x); o.y = f2bf(v.y); o.z = f2bf(v.z); o.w = f2bf(v.w);
        *(ushort4*)p = o;
    }
    __syncthreads();

    const int lane = t & 63;
    const int w = t >> 6;
    const int m = lane & 15;
    const int q = lane >> 4;

    f32x4 acc[4];
#pragma unroll
    for (int nt = 0; nt < 4; ++nt) acc[nt] = (f32x4){0.f, 0.f, 0.f, 0.f};

#pragma unroll
    for (int ks = 0; ks < 8; ++ks) {
        bf16x8 A = *(const bf16x8*)&Xl[(16 * w + m) * LDK + ks * 32 + q * 8];
#pragma unroll
        for (int nt = 0; nt < 4; ++nt) {
            bf16x8 B = *(const bf16x8*)&Wl[(16 * nt + m) * LDK + ks * 32 + q * 8];
            acc[nt] = __builtin_amdgcn_mfma_f32_16x16x32_bf16(A, B, acc[nt], 0, 0, 0);
        }
    }

#pragma unroll
    for (int nt = 0; nt < 4; ++nt) {
#pragma unroll
        for (int r = 0; r < 4; ++r) {
            int gr = row0 + 16 * w + q * 4 + r;
            if (gr < n) h[(size_t)gr * C_OUT + nt * 16 + m] = f2bf(acc[nt][r]);
        }
    }
}

// ---------------- gather: 1 wave per node, 2 edges/iter (half-wave each) ----------------
__global__ __launch_bounds__(256) void k_gather(const int* __restrict__ rowptr,
                                                const int* __restrict__ eidx,
                                                const unsigned short* __restrict__ h,
                                                const float* __restrict__ dinv,
                                                const float* __restrict__ bias,
                                                float* __restrict__ out, int n) {
    int node = blockIdx.x * 4 + (threadIdx.x >> 6);
    if (node >= n) return;
    int lane = threadIdx.x & 63;
    int half = lane >> 5;
    int c2 = (lane & 31) * 2;

    int beg = rowptr[node];
    int end = rowptr[node + 1];
    float di = dinv[node];
    float ax = 0.f, ay = 0.f;

    int j = beg;
    for (; j + 7 < end; j += 8) {
        int s0 = eidx[j + half];
        int s1 = eidx[j + 2 + half];
        int s2 = eidx[j + 4 + half];
        int s3 = eidx[j + 6 + half];
        float d0 = dinv[s0], d1 = dinv[s1], d2 = dinv[s2], d3 = dinv[s3];
        unsigned h0 = *(const unsigned*)&h[(size_t)s0 * C_OUT + c2];
        unsigned h1 = *(const unsigned*)&h[(size_t)s1 * C_OUT + c2];
        unsigned h2 = *(const unsigned*)&h[(size_t)s2 * C_OUT + c2];
        unsigned h3 = *(const unsigned*)&h[(size_t)s3 * C_OUT + c2];
        ax += bflo(h0) * d0; ay += bfhi(h0) * d0;
        ax += bflo(h1) * d1; ay += bfhi(h1) * d1;
        ax += bflo(h2) * d2; ay += bfhi(h2) * d2;
        ax += bflo(h3) * d3; ay += bfhi(h3) * d3;
    }
    for (; j < end; j += 2) {
        int rem = end - j;
        int idx = j + ((half < rem) ? half : 0);
        int s = eidx[idx];
        float d = (half < rem) ? dinv[s] : 0.f;
        unsigned hv = *(const unsigned*)&h[(size_t)s * C_OUT + c2];
        ax += bflo(hv) * d; ay += bfhi(hv) * d;
    }
    ax += __shfl_xor(ax, 32, 64);
    ay += __shfl_xor(ay, 32, 64);
    if (half == 0) {
        unsigned sv = *(const unsigned*)&h[(size_t)node * C_OUT + c2];
        float2 bb = *(const float2*)&bias[c2];
        float2 o;
        o.x = ax * di + bflo(sv) * di * di + bb.x;
        o.y = ay * di + bfhi(sv) * di * di + bb.y;
        *(float2*)&out[(size_t)node * C_OUT + c2] = o;
    }
}

extern "C" void kernel_launch(void* const* d_in, const int* in_sizes, int n_in,
                              void* d_out, int out_size, void* d_ws, size_t ws_size,
                              hipStream_t stream) {
    const float* x = (const float*)d_in[0];
    const int* ei = (const int*)d_in[1];
    const float* W = (const float*)d_in[2];
    const float* bias = (const float*)d_in[3];
    float* out = (float*)d_out;

    const int n = in_sizes[0] / C_IN;  // 100000
    const int e = in_sizes[1] / 2;     // 3200000
    const int* src = ei;
    const int* dst = ei + e;

    const int nbin = (e + CHUNK - 1) / CHUNK;   // 391
    const int nbuck = (n + NPB - 1) / NPB;      // 782

    char* w = (char*)d_ws;
    unsigned short* h = (unsigned short*)w;  w += (size_t)n * C_OUT * 2;   // 12.8 MB
    int* sorted = (int*)w;                   w += (size_t)e * 4;           // 12.8 MB
    int* eidx = (int*)w;                     w += (size_t)e * 4;           // 12.8 MB
    float* dinv = (float*)w;                 w += (size_t)n * 4;
    int* rowptr = (int*)w;                   w += (size_t)(n + 1) * 4;
    int* table = (int*)w;                    w += (size_t)nbin * NB * 4;   // 1.6 MB
    int* tot = (int*)w;                      w += NB * 4;
    int* gbase = (int*)w;                    w += (NB + 1) * 4;

    k_hist2<<<nbin, 256, 0, stream>>>(dst, table, e);
    kA2<<<NB, 256, 0, stream>>>(table, tot, nbin);
    kB<<<1, 1024, 0, stream>>>(tot, gbase, e);
    k_bin2<<<nbin, 256, 0, stream>>>(src, dst, table, gbase, sorted, e);
    k_gemm<<<(n + 63) / 64, 256, 0, stream>>>(x, W, h, n);
    k_sort2<<<nbuck, 256, 0, stream>>>(sorted, gbase, eidx, rowptr, dinv, n, e);
    k_gather<<<(n + 3) / 4, 256, 0, stream>>>(rowptr, eidx, h, dinv, bias, out, n);
}

// Round 10
// 378.299 us; speedup vs baseline: 1.2613x; 1.0155x over previous
//
#include <hip/hip_runtime.h>

#define C_IN 256
#define C_OUT 64
#define BSH 7                 // bucket = dst >> 7  (128 nodes/bucket)
#define NPB 128               // nodes per bucket
#define NB 1024               // max buckets (n <= 131072)
#define CHUNK 4096            // edges per binning block (782 blocks -> 3/CU)
#define ROWS 4                // table rows per thread in kA2 (256*4 >= nbin)
#define LDK 264               // padded row stride (ushorts): 256 + 8 -> 528 B

typedef short bf16x8 __attribute__((ext_vector_type(8)));
typedef float f32x4 __attribute__((ext_vector_type(4)));

__device__ __forceinline__ unsigned short f2bf(float f) {
    unsigned u = __builtin_bit_cast(unsigned, f);
    u = (u + 0x7FFFu + ((u >> 16) & 1u)) >> 16;
    return (unsigned short)u;
}
__device__ __forceinline__ float bflo(unsigned u) {
    return __builtin_bit_cast(float, u << 16);
}
__device__ __forceinline__ float bfhi(unsigned u) {
    return __builtin_bit_cast(float, u & 0xffff0000u);
}

// ---------------- per-(block,bucket) histogram table ----------------
__global__ __launch_bounds__(256) void k_hist2(const int* __restrict__ dst,
                                               int* __restrict__ table, int e) {
    __shared__ int cnt[NB];
    for (int j = threadIdx.x; j < NB; j += 256) cnt[j] = 0;
    __syncthreads();
    int b0 = blockIdx.x * CHUNK;
#pragma unroll 4
    for (int k = 0; k < CHUNK / 256; ++k) {
        int i = b0 + k * 256 + threadIdx.x;
        if (i < e) atomicAdd(&cnt[dst[i] >> BSH], 1);
    }
    __syncthreads();
    int* row = table + (size_t)blockIdx.x * NB;
    for (int j = threadIdx.x; j < NB; j += 256) row[j] = cnt[j];
}

// ---------------- column-wise exclusive scan: one block per bucket ----------------
// nbin <= 256*ROWS. 4 independent loads/thread + block scan of partials.
__global__ __launch_bounds__(256) void kA2(int* __restrict__ table,
                                           int* __restrict__ tot, int nbin) {
    __shared__ int part[256];
    int bucket = blockIdx.x;
    int t = threadIdx.x;
    int v[ROWS];
    int s = 0;
#pragma unroll
    for (int i = 0; i < ROWS; ++i) {
        int r = t * ROWS + i;
        int x = (r < nbin) ? table[(size_t)r * NB + bucket] : 0;
        v[i] = s;
        s += x;
    }
    part[t] = s;
    __syncthreads();
    for (int off = 1; off < 256; off <<= 1) {
        int u = (t >= off) ? part[t - off] : 0;
        __syncthreads();
        part[t] += u;
        __syncthreads();
    }
    int base = part[t] - s;  // exclusive over threads
#pragma unroll
    for (int i = 0; i < ROWS; ++i) {
        int r = t * ROWS + i;
        if (r < nbin) table[(size_t)r * NB + bucket] = v[i] + base;
    }
    if (t == 255) tot[bucket] = part[255];
}

// ---------------- bucket totals -> compact gbase ----------------
__global__ __launch_bounds__(1024) void kB(const int* __restrict__ tot,
                                           int* __restrict__ gbase, int e) {
    __shared__ int l[NB];
    int t = threadIdx.x;
    int v = tot[t];
    l[t] = v;
    __syncthreads();
    for (int off = 1; off < NB; off <<= 1) {
        int u = (t >= off) ? l[t - off] : 0;
        __syncthreads();
        l[t] += u;
        __syncthreads();
    }
    gbase[t] = l[t] - v;  // exclusive
    if (t == NB - 1) gbase[NB] = e;
}

// ---------------- single-pass atomic-free multisplit ----------------
__global__ __launch_bounds__(256) void k_bin2(const int* __restrict__ src,
                                              const int* __restrict__ dst,
                                              const int* __restrict__ table,
                                              const int* __restrict__ gbase,
                                              int* __restrict__ sorted, int e) {
    __shared__ int cur[NB];
    const int* row = table + (size_t)blockIdx.x * NB;
    for (int j = threadIdx.x; j < NB; j += 256) cur[j] = row[j] + gbase[j];
    __syncthreads();
    int b0 = blockIdx.x * CHUNK;
#pragma unroll 4
    for (int k = 0; k < CHUNK / 256; ++k) {
        int i = b0 + k * 256 + threadIdx.x;
        if (i < e) {
            int d = dst[i];
            int bb = d >> BSH;
            int off = atomicAdd(&cur[bb], 1);
            sorted[off] = (src[i] << BSH) | (d & (NPB - 1));
        }
    }
}

// ---------------- in-bucket counting sort -> per-node CSR, plus dinv ----------------
__global__ __launch_bounds__(256) void k_sort2(const int* __restrict__ sorted,
                                               const int* __restrict__ gbase,
                                               int* __restrict__ eidx,
                                               int* __restrict__ rowptr,
                                               float* __restrict__ dinv, int n, int e) {
    __shared__ int cnt[NPB];
    __shared__ int sc[NPB];
    __shared__ int cur[NPB];
    int b = blockIdx.x;
    int node0 = b * NPB;
    int range = min(NPB, n - node0);
    int inbase = gbase[b];
    int m_b = gbase[b + 1] - inbase;
    if (threadIdx.x < NPB) cnt[threadIdx.x] = 0;
    __syncthreads();
    for (int j = threadIdx.x; j < m_b; j += 256)
        atomicAdd(&cnt[sorted[inbase + j] & (NPB - 1)], 1);
    __syncthreads();
    if (threadIdx.x < NPB) sc[threadIdx.x] = cnt[threadIdx.x];
    __syncthreads();
    for (int off = 1; off < NPB; off <<= 1) {
        int t = (threadIdx.x < NPB && threadIdx.x >= off) ? sc[threadIdx.x - off] : 0;
        __syncthreads();
        if (threadIdx.x < NPB) sc[threadIdx.x] += t;
        __syncthreads();
    }
    if (threadIdx.x < NPB) {
        int excl = inbase + sc[threadIdx.x] - cnt[threadIdx.x];
        cur[threadIdx.x] = excl;
        if (threadIdx.x < range) {
            rowptr[node0 + threadIdx.x] = excl;
            dinv[node0 + threadIdx.x] = rsqrtf((float)(cnt[threadIdx.x] + 1));
        }
    }
    __syncthreads();
    for (int j = threadIdx.x; j < m_b; j += 256) {
        int v = sorted[inbase + j];
        int pos = atomicAdd(&cur[v & (NPB - 1)], 1);
        eidx[pos] = v >> BSH;
    }
    if (b == 0 && threadIdx.x == 0) rowptr[n] = e;
}

// ---------------- h = x @ W via bf16 MFMA (bf16 output) ----------------
__global__ __launch_bounds__(256) void k_gemm(const float* __restrict__ x,
                                              const float* __restrict__ W,
                                              unsigned short* __restrict__ h, int n) {
    __shared__ unsigned short Xl[64 * LDK];
    __shared__ unsigned short Wl[64 * LDK];  // transposed: Wl[n][k]

    const int t = threadIdx.x;
    const int row0 = blockIdx.x * 64;

#pragma unroll
    for (int i = 0; i < 16; ++i) {
        int f = i * 256 + t;
        int k = f >> 4;
        int n4 = (f & 15) * 4;
        float4 v = ((const float4*)W)[f];
        Wl[(n4 + 0) * LDK + k] = f2bf(v.x);
        Wl[(n4 + 1) * LDK + k] = f2bf(v.y);
        Wl[(n4 + 2) * LDK + k] = f2bf(v.z);
        Wl[(n4 + 3) * LDK + k] = f2bf(v.w);
    }
#pragma unroll
    for (int i = 0; i < 16; ++i) {
        int f = i * 256 + t;
        int row = f >> 6;
        int c4 = f & 63;
        int gr = row0 + row;
        float4 v = (gr < n) ? ((const float4*)x)[(size_t)gr * 64 + c4]
                            : make_float4(0.f, 0.f, 0.f, 0.f);
        unsigned short* p = &Xl[row * LDK + c4 * 4];
        ushort4 o;
        o.x = f2bf(v.x); o.y = f2bf(v.y); o.z = f2bf(v.z); o.w = f2bf(v.w);
        *(ushort4*)p = o;
    }
    __syncthreads();

    const int lane = t & 63;
    const int w = t >> 6;
    const int m = lane & 15;
    const int q = lane >> 4;

    f32x4 acc[4];
#pragma unroll
    for (int nt = 0; nt < 4; ++nt) acc[nt] = (f32x4){0.f, 0.f, 0.f, 0.f};

#pragma unroll
    for (int ks = 0; ks < 8; ++ks) {
        bf16x8 A = *(const bf16x8*)&Xl[(16 * w + m) * LDK + ks * 32 + q * 8];
#pragma unroll
        for (int nt = 0; nt < 4; ++nt) {
            bf16x8 B = *(const bf16x8*)&Wl[(16 * nt + m) * LDK + ks * 32 + q * 8];
            acc[nt] = __builtin_amdgcn_mfma_f32_16x16x32_bf16(A, B, acc[nt], 0, 0, 0);
        }
    }

#pragma unroll
    for (int nt = 0; nt < 4; ++nt) {
#pragma unroll
        for (int r = 0; r < 4; ++r) {
            int gr = row0 + 16 * w + q * 4 + r;
            if (gr < n) h[(size_t)gr * C_OUT + nt * 16 + m] = f2bf(acc[nt][r]);
        }
    }
}

// ---------------- gather: 1 wave/node, 4 edges in flight (quarter-wave each, 4 ch/lane) ----
__global__ __launch_bounds__(256) void k_gather(const int* __restrict__ rowptr,
                                                const int* __restrict__ eidx,
                                                const unsigned short* __restrict__ h,
                                                const float* __restrict__ dinv,
                                                const float* __restrict__ bias,
                                                float* __restrict__ out, int n) {
    int node = blockIdx.x * 4 + (threadIdx.x >> 6);
    if (node >= n) return;
    int lane = threadIdx.x & 63;
    int q = lane >> 4;          // 0..3 quarter
    int c4 = (lane & 15) * 4;   // channel base 0..60

    int beg = rowptr[node];
    int end = rowptr[node + 1];
    float di = dinv[node];
    float a0 = 0.f, a1 = 0.f, a2 = 0.f, a3 = 0.f;

    int j = beg;
    for (; j + 7 < end; j += 8) {
        int sa = eidx[j + q];
        int sb = eidx[j + 4 + q];
        float da = dinv[sa], db = dinv[sb];
        uint2 ha = *(const uint2*)&h[(size_t)sa * C_OUT + c4];
        uint2 hb = *(const uint2*)&h[(size_t)sb * C_OUT + c4];
        a0 += bflo(ha.x) * da; a1 += bfhi(ha.x) * da;
        a2 += bflo(ha.y) * da; a3 += bfhi(ha.y) * da;
        a0 += bflo(hb.x) * db; a1 += bfhi(hb.x) * db;
        a2 += bflo(hb.y) * db; a3 += bfhi(hb.y) * db;
    }
    for (; j < end; j += 4) {
        int rem = end - j;
        int idx = j + ((q < rem) ? q : 0);
        int s = eidx[idx];
        float d = (q < rem) ? dinv[s] : 0.f;
        uint2 hv = *(const uint2*)&h[(size_t)s * C_OUT + c4];
        a0 += bflo(hv.x) * d; a1 += bfhi(hv.x) * d;
        a2 += bflo(hv.y) * d; a3 += bfhi(hv.y) * d;
    }
    a0 += __shfl_xor(a0, 16, 64); a0 += __shfl_xor(a0, 32, 64);
    a1 += __shfl_xor(a1, 16, 64); a1 += __shfl_xor(a1, 32, 64);
    a2 += __shfl_xor(a2, 16, 64); a2 += __shfl_xor(a2, 32, 64);
    a3 += __shfl_xor(a3, 16, 64); a3 += __shfl_xor(a3, 32, 64);
    if (q == 0) {
        uint2 sv = *(const uint2*)&h[(size_t)node * C_OUT + c4];
        float4 bb = *(const float4*)&bias[c4];
        float dd = di * di;
        float4 o;
        o.x = a0 * di + bflo(sv.x) * dd + bb.x;
        o.y = a1 * di + bfhi(sv.x) * dd + bb.y;
        o.z = a2 * di + bflo(sv.y) * dd + bb.z;
        o.w = a3 * di + bfhi(sv.y) * dd + bb.w;
        *(float4*)&out[(size_t)node * C_OUT + c4] = o;
    }
}

extern "C" void kernel_launch(void* const* d_in, const int* in_sizes, int n_in,
                              void* d_out, int out_size, void* d_ws, size_t ws_size,
                              hipStream_t stream) {
    const float* x = (const float*)d_in[0];
    const int* ei = (const int*)d_in[1];
    const float* W = (const float*)d_in[2];
    const float* bias = (const float*)d_in[3];
    float* out = (float*)d_out;

    const int n = in_sizes[0] / C_IN;  // 100000
    const int e = in_sizes[1] / 2;     // 3200000
    const int* src = ei;
    const int* dst = ei + e;

    const int nbin = (e + CHUNK - 1) / CHUNK;   // 782
    const int nbuck = (n + NPB - 1) / NPB;      // 782

    char* w = (char*)d_ws;
    unsigned short* h = (unsigned short*)w;  w += (size_t)n * C_OUT * 2;   // 12.8 MB
    int* sorted = (int*)w;                   w += (size_t)e * 4;           // 12.8 MB
    int* eidx = (int*)w;                     w += (size_t)e * 4;           // 12.8 MB
    float* dinv = (float*)w;                 w += (size_t)n * 4;
    int* rowptr = (int*)w;                   w += (size_t)(n + 1) * 4;
    int* table = (int*)w;                    w += (size_t)nbin * NB * 4;   // 3.2 MB
    int* tot = (int*)w;                      w += NB * 4;
    int* gbase = (int*)w;                    w += (NB + 1) * 4;

    k_hist2<<<nbin, 256, 0, stream>>>(dst, table, e);
    kA2<<<NB, 256, 0, stream>>>(table, tot, nbin);
    kB<<<1, 1024, 0, stream>>>(tot, gbase, e);
    k_bin2<<<nbin, 256, 0, stream>>>(src, dst, table, gbase, sorted, e);
    k_gemm<<<(n + 63) / 64, 256, 0, stream>>>(x, W, h, n);
    k_sort2<<<nbuck, 256, 0, stream>>>(sorted, gbase, eidx, rowptr, dinv, n, e);
    k_gather<<<(n + 3) / 4, 256, 0, stream>>>(rowptr, eidx, h, dinv, bias, out, n);
}